// Round 1
// baseline (112.772 us; speedup 1.0000x reference)
//
#include <hip/hip_runtime.h>
#include <math.h>

// Problem constants (B, D, C) from the reference.
#define NB 4096
#define ND 3072
#define NC 10
#define NM 9   // C-1

static constexpr float kEps     = 0.1f;
static constexpr float kNumStab = 1e-6f;
static constexpr float kAlpha   = 1.0f - (float)NC * kNumStab;  // 1 - C*num_stab
static constexpr float kInvSqrtC = 0.31622776601683794f;        // 1/sqrt(10)

// ---------------------------------------------------------------------------
// Kernel 1: G = W^T W   (10x10). One block per (j,k) entry, block-reduce over D.
// W is 123 KB -> fully L2-resident; this kernel is noise-level cost.
// ---------------------------------------------------------------------------
__global__ void gram_kernel(const float* __restrict__ W, float* __restrict__ G) {
    const int j = blockIdx.x / NC;
    const int k = blockIdx.x % NC;
    float acc = 0.0f;
    for (int d = threadIdx.x; d < ND; d += 256) {
        acc += W[d * NC + j] * W[d * NC + k];
    }
    #pragma unroll
    for (int off = 32; off > 0; off >>= 1) acc += __shfl_xor(acc, off, 64);
    __shared__ float part[4];
    const int lane = threadIdx.x & 63;
    const int wv   = threadIdx.x >> 6;
    if (lane == 0) part[wv] = acc;
    __syncthreads();
    if (threadIdx.x == 0) G[blockIdx.x] = part[0] + part[1] + part[2] + part[3];
}

// ---------------------------------------------------------------------------
// Kernel 2: main. Block = 256 threads = 4 waves. Block owns 4 samples.
// Wave w accumulates partial z over d in [w*768, w*768+768) for all 4 samples
// (4 samples per W-row read -> W L2 traffic cut 4x). Butterfly-reduce in-wave,
// combine across waves in LDS, then 4 threads run the analytic epilogue.
// ---------------------------------------------------------------------------
__global__ __launch_bounds__(256) void jacreg_kernel(
        const float* __restrict__ data, const float* __restrict__ W,
        const float* __restrict__ G, float* __restrict__ out) {
    __shared__ float Gs[100];
    __shared__ float zpart[4][40];
    __shared__ float zsum[40];
    __shared__ float regs[4];

    const int tid  = threadIdx.x;
    const int lane = tid & 63;
    const int wv   = tid >> 6;
    if (tid < 100) Gs[tid] = G[tid];

    const int s0 = blockIdx.x * 4;

    float acc[4][10];
    #pragma unroll
    for (int s = 0; s < 4; ++s)
        #pragma unroll
        for (int k = 0; k < NC; ++k) acc[s][k] = 0.0f;

    const int dwave = wv * 768;
    #pragma unroll
    for (int it = 0; it < 3; ++it) {
        const int d0 = dwave + it * 256 + lane * 4;   // 64 lanes * float4 = 256 d per iter
        float4 xv[4];
        #pragma unroll
        for (int s = 0; s < 4; ++s) {
            xv[s] = *reinterpret_cast<const float4*>(
                        &data[(size_t)(s0 + s) * ND + d0]);
        }
        #pragma unroll
        for (int dd = 0; dd < 4; ++dd) {
            const float* wr = &W[(size_t)(d0 + dd) * NC];   // row base: 40B -> 8B aligned
            const float2 w01 = *reinterpret_cast<const float2*>(wr);
            const float2 w23 = *reinterpret_cast<const float2*>(wr + 2);
            const float2 w45 = *reinterpret_cast<const float2*>(wr + 4);
            const float2 w67 = *reinterpret_cast<const float2*>(wr + 6);
            const float2 w89 = *reinterpret_cast<const float2*>(wr + 8);
            const float wk[10] = {w01.x, w01.y, w23.x, w23.y, w45.x,
                                  w45.y, w67.x, w67.y, w89.x, w89.y};
            #pragma unroll
            for (int s = 0; s < 4; ++s) {
                const float xs[4] = {xv[s].x, xv[s].y, xv[s].z, xv[s].w};
                const float xd = xs[dd];
                #pragma unroll
                for (int k = 0; k < NC; ++k)
                    acc[s][k] = fmaf(xd, wk[k], acc[s][k]);
            }
        }
    }

    // In-wave butterfly reduction of all 40 partials.
    #pragma unroll
    for (int s = 0; s < 4; ++s) {
        #pragma unroll
        for (int k = 0; k < NC; ++k) {
            float v = acc[s][k];
            #pragma unroll
            for (int off = 32; off > 0; off >>= 1) v += __shfl_xor(v, off, 64);
            acc[s][k] = v;
        }
    }

    // Lane l (<40) exports value #l (compile-time-unrolled select; no scratch).
    if (lane < 40) {
        float v = 0.0f;
        #pragma unroll
        for (int s = 0; s < 4; ++s)
            #pragma unroll
            for (int k = 0; k < NC; ++k)
                if (lane == s * NC + k) v = acc[s][k];
        zpart[wv][lane] = v;
    }
    __syncthreads();
    if (tid < 40)
        zsum[tid] = zpart[0][tid] + zpart[1][tid] + zpart[2][tid] + zpart[3][tid];
    __syncthreads();

    // Analytic epilogue: thread s handles sample s0+s.
    if (tid < 4) {
        float z[NC];
        #pragma unroll
        for (int k = 0; k < NC; ++k) z[k] = zsum[tid * NC + k];

        float zm = z[0];
        #pragma unroll
        for (int k = 1; k < NC; ++k) zm = fmaxf(zm, z[k]);
        float e[NC], Zs = 0.0f;
        #pragma unroll
        for (int k = 0; k < NC; ++k) { e[k] = expf(z[k] - zm); Zs += e[k]; }
        const float inv = 1.0f / Zs;

        float sg[NC], p[NC], sq[NC], u[NC];
        #pragma unroll
        for (int k = 0; k < NC; ++k) {
            sg[k] = e[k] * inv;                 // softmax probs (sigma)
            p[k]  = kAlpha * sg[k] + kNumStab;  // stabilized probs
            sq[k] = sqrtf(p[k]);                // s
            u[k]  = sg[k] / sq[k];              // sigma / s
        }
        const float q = 1.0f - sq[NM];

        // v = G*sigma, t = sigma^T G sigma
        float v[NC], t = 0.0f;
        #pragma unroll
        for (int k = 0; k < NC; ++k) {
            float a = 0.0f;
            #pragma unroll
            for (int j = 0; j < NC; ++j) a = fmaf(Gs[k * NC + j], sg[j], a);
            v[k] = a;
            t = fmaf(sg[k], a, t);
        }
        const float vM = v[NM], uM = u[NM];
        const float QMM = Gs[NC * NC - 1] - 2.0f * vM + t;

        float sumJ = 0.0f;
        #pragma unroll
        for (int i = 0; i < NM; ++i) {
            const float Qii = Gs[i * NC + i] - 2.0f * v[i] + t;
            const float QiM = Gs[i * NC + NM] - v[i] - vM + t;
            const float r = sq[i] / q;
            sumJ += u[i] * u[i] * Qii
                  + 2.0f * u[i] * uM * r * QiM
                  + uM * uM * r * r * QMM;
        }
        const float jn = (kAlpha / q) * sqrtf(fmaxf(sumJ, 0.0f));

        float ssum = 0.0f;
        #pragma unroll
        for (int k = 0; k < NC; ++k) ssum += sq[k];
        const float ac = fminf(1.0f, fmaxf(-1.0f, ssum * kInvSqrtC));
        const float delta = 2.0f * acosf(ac);

        float psum = 0.0f;
        #pragma unroll
        for (int k = 0; k < NM; ++k) psum += p[k];
        const float rho = (2.0f * q - psum) / q;

        const float a = jn - delta / (rho * kEps);
        regs[tid] = (a > 0.0f) ? a : expm1f(a);
    }
    __syncthreads();
    if (tid == 0) {
        const float bs = (regs[0] + regs[1] + regs[2] + regs[3]) * (1.0f / (float)NB);
        atomicAdd(out, bs);
    }
}

extern "C" void kernel_launch(void* const* d_in, const int* in_sizes, int n_in,
                              void* d_out, int out_size, void* d_ws, size_t ws_size,
                              hipStream_t stream) {
    const float* data = (const float*)d_in[0];
    const float* W    = (const float*)d_in[1];
    float* out = (float*)d_out;
    float* G   = (float*)d_ws;   // 100 floats of scratch for the Gram matrix

    // d_out is re-poisoned to 0xAA before every timed launch -> zero it ourselves.
    hipMemsetAsync(out, 0, sizeof(float), stream);
    gram_kernel<<<NC * NC, 256, 0, stream>>>(W, G);
    jacreg_kernel<<<NB / 4, 256, 0, stream>>>(data, W, G, out);
}

// Round 2
// 98.509 us; speedup vs baseline: 1.1448x; 1.1448x over previous
//
#include <hip/hip_runtime.h>
#include <math.h>

// Problem constants (B, D, C) from the reference.
#define NB 4096
#define ND 3072
#define NC 10
#define NM 9   // C-1

static constexpr float kEps      = 0.1f;
static constexpr float kNumStab  = 1e-6f;
static constexpr float kAlpha    = 1.0f - (float)NC * kNumStab;  // 1 - C*num_stab
static constexpr float kInvSqrtC = 0.31622776601683794f;         // 1/sqrt(10)

// ---------------------------------------------------------------------------
// Kernel 1: G = W^T W (10x10). One block per (j,k) entry, block-reduce over D.
// W is 120 KB -> L2-resident; noise-level cost.
// ---------------------------------------------------------------------------
__global__ void gram_kernel(const float* __restrict__ W, float* __restrict__ G) {
    const int j = blockIdx.x / NC;
    const int k = blockIdx.x % NC;
    float acc = 0.0f;
    for (int d = threadIdx.x; d < ND; d += 256) {
        acc += W[d * NC + j] * W[d * NC + k];
    }
    #pragma unroll
    for (int off = 32; off > 0; off >>= 1) acc += __shfl_xor(acc, off, 64);
    __shared__ float part[4];
    const int lane = threadIdx.x & 63;
    const int wv   = threadIdx.x >> 6;
    if (lane == 0) part[wv] = acc;
    __syncthreads();
    if (threadIdx.x == 0) G[blockIdx.x] = part[0] + part[1] + part[2] + part[3];
}

// ---------------------------------------------------------------------------
// Kernel 2: main. Block = 512 threads = 8 waves, grid = 256 (1 block/CU).
// Whole W is staged TRANSPOSED in LDS (Wt[k][d], 120 KB) -> the inner loop
// reads W via conflict-free ds_read_b128 (lane stride 16 B) instead of the
// scattered 160 B-stride global loads that dominated R1.
// Each wave owns 2 samples over the FULL D range -> every lane ends the
// butterfly with the complete z[10] for its wave's samples; lanes 0/1 run the
// analytic epilogue with zero cross-wave traffic.
// ---------------------------------------------------------------------------
__global__ __launch_bounds__(512) void jacreg_kernel(
        const float* __restrict__ data, const float* __restrict__ W,
        const float* __restrict__ G, float* __restrict__ out) {
    __shared__ float Wts[NC * ND];   // 122880 B, k-major: Wts[k*ND + d]
    __shared__ float Gs[100];
    __shared__ float regs[16];

    const int tid  = threadIdx.x;
    const int lane = tid & 63;
    const int wv   = tid >> 6;

    if (tid < 100) Gs[tid] = G[tid];

    // Stage W -> LDS transposed. Coalesced float4 global reads; scattered
    // one-time LDS scalar writes (60 per thread).
    for (int i = tid; i < (ND * NC) / 4; i += 512) {
        const float4 w4 = reinterpret_cast<const float4*>(W)[i];
        const float* wp = reinterpret_cast<const float*>(&w4);
        const int e0 = i * 4;
        #pragma unroll
        for (int j = 0; j < 4; ++j) {
            const int e = e0 + j;
            Wts[(e % NC) * ND + (e / NC)] = wp[j];
        }
    }
    __syncthreads();

    const int s0 = blockIdx.x * 16 + wv * 2;     // this wave's 2 samples
    const float* __restrict__ r0 = data + (size_t)s0 * ND;
    const float* __restrict__ r1 = r0 + ND;

    float acc[2][NC];
    #pragma unroll
    for (int s = 0; s < 2; ++s)
        #pragma unroll
        for (int k = 0; k < NC; ++k) acc[s][k] = 0.0f;

    // 12 iterations of 256 d each (64 lanes x float4). Manual prefetch of the
    // next iteration's data so global loads overlap the FMA+LDS work.
    float4 x0 = reinterpret_cast<const float4*>(r0)[lane];
    float4 x1 = reinterpret_cast<const float4*>(r1)[lane];
    for (int it = 0; it < 12; ++it) {
        const int nit = (it == 11) ? 11 : it + 1;
        const float4 nx0 = reinterpret_cast<const float4*>(r0)[nit * 64 + lane];
        const float4 nx1 = reinterpret_cast<const float4*>(r1)[nit * 64 + lane];

        const int dbase = it * 256 + lane * 4;
        #pragma unroll
        for (int k = 0; k < NC; ++k) {
            const float4 wt = *reinterpret_cast<const float4*>(&Wts[k * ND + dbase]);
            acc[0][k] = fmaf(x0.x, wt.x, acc[0][k]);
            acc[0][k] = fmaf(x0.y, wt.y, acc[0][k]);
            acc[0][k] = fmaf(x0.z, wt.z, acc[0][k]);
            acc[0][k] = fmaf(x0.w, wt.w, acc[0][k]);
            acc[1][k] = fmaf(x1.x, wt.x, acc[1][k]);
            acc[1][k] = fmaf(x1.y, wt.y, acc[1][k]);
            acc[1][k] = fmaf(x1.z, wt.z, acc[1][k]);
            acc[1][k] = fmaf(x1.w, wt.w, acc[1][k]);
        }
        x0 = nx0;
        x1 = nx1;
    }

    // In-wave butterfly: every lane ends with the full z for both samples.
    #pragma unroll
    for (int s = 0; s < 2; ++s)
        #pragma unroll
        for (int k = 0; k < NC; ++k) {
            float v = acc[s][k];
            #pragma unroll
            for (int off = 32; off > 0; off >>= 1) v += __shfl_xor(v, off, 64);
            acc[s][k] = v;
        }

    // Analytic epilogue: lane 0 -> sample s0, lane 1 -> sample s0+1.
    if (lane < 2) {
        float z[NC];
        #pragma unroll
        for (int k = 0; k < NC; ++k) z[k] = (lane == 0) ? acc[0][k] : acc[1][k];

        float zm = z[0];
        #pragma unroll
        for (int k = 1; k < NC; ++k) zm = fmaxf(zm, z[k]);
        float e[NC], Zs = 0.0f;
        #pragma unroll
        for (int k = 0; k < NC; ++k) { e[k] = expf(z[k] - zm); Zs += e[k]; }
        const float inv = 1.0f / Zs;

        float sg[NC], p[NC], sq[NC], u[NC];
        #pragma unroll
        for (int k = 0; k < NC; ++k) {
            sg[k] = e[k] * inv;                 // softmax probs (sigma)
            p[k]  = kAlpha * sg[k] + kNumStab;  // stabilized probs
            sq[k] = sqrtf(p[k]);                // s
            u[k]  = sg[k] / sq[k];              // sigma / s
        }
        const float q = 1.0f - sq[NM];

        // v = G*sigma, t = sigma^T G sigma
        float v[NC], t = 0.0f;
        #pragma unroll
        for (int k = 0; k < NC; ++k) {
            float a = 0.0f;
            #pragma unroll
            for (int j = 0; j < NC; ++j) a = fmaf(Gs[k * NC + j], sg[j], a);
            v[k] = a;
            t = fmaf(sg[k], a, t);
        }
        const float vM = v[NM], uM = u[NM];
        const float QMM = Gs[NC * NC - 1] - 2.0f * vM + t;

        float sumJ = 0.0f;
        #pragma unroll
        for (int i = 0; i < NM; ++i) {
            const float Qii = Gs[i * NC + i] - 2.0f * v[i] + t;
            const float QiM = Gs[i * NC + NM] - v[i] - vM + t;
            const float r = sq[i] / q;
            sumJ += u[i] * u[i] * Qii
                  + 2.0f * u[i] * uM * r * QiM
                  + uM * uM * r * r * QMM;
        }
        const float jn = (kAlpha / q) * sqrtf(fmaxf(sumJ, 0.0f));

        float ssum = 0.0f;
        #pragma unroll
        for (int k = 0; k < NC; ++k) ssum += sq[k];
        const float ac = fminf(1.0f, fmaxf(-1.0f, ssum * kInvSqrtC));
        const float delta = 2.0f * acosf(ac);

        float psum = 0.0f;
        #pragma unroll
        for (int k = 0; k < NM; ++k) psum += p[k];
        const float rho = (2.0f * q - psum) / q;

        const float a = jn - delta / (rho * kEps);
        regs[wv * 2 + lane] = (a > 0.0f) ? a : expm1f(a);
    }
    __syncthreads();
    if (tid == 0) {
        float bs = 0.0f;
        #pragma unroll
        for (int i = 0; i < 16; ++i) bs += regs[i];
        atomicAdd(out, bs * (1.0f / (float)NB));
    }
}

extern "C" void kernel_launch(void* const* d_in, const int* in_sizes, int n_in,
                              void* d_out, int out_size, void* d_ws, size_t ws_size,
                              hipStream_t stream) {
    const float* data = (const float*)d_in[0];
    const float* W    = (const float*)d_in[1];
    float* out = (float*)d_out;
    float* G   = (float*)d_ws;   // 100 floats of scratch for the Gram matrix

    // d_out is re-poisoned to 0xAA before every timed launch -> zero it ourselves.
    hipMemsetAsync(out, 0, sizeof(float), stream);
    gram_kernel<<<NC * NC, 256, 0, stream>>>(W, G);
    jacreg_kernel<<<NB / 16, 512, 0, stream>>>(data, W, G, out);
}